// Round 9
// baseline (296.250 us; speedup 1.0000x reference)
//
#include <hip/hip_runtime.h>
#include <stdint.h>

#define N_NODES 50000
#define N_EDGES 800000
#define M_PAD   50048   // 391 * 128 (= 3128 * 16)
#define NREP    4       // counter replicas / buckets per node
#define RCAP    32      // per-replica bucket capacity (ushort) = 64B = 1 line
#define CSTR    50048   // cnt replica stride
#define TSTR    264     // LDS intermediate-tile row stride (bf16)

typedef __attribute__((ext_vector_type(8))) short bf16x8;
typedef __attribute__((ext_vector_type(4))) float f32x4;

__device__ __forceinline__ unsigned short f2b(float f){
    unsigned int u = __builtin_bit_cast(unsigned int, f);
    u += 0x7fffu + ((u >> 16) & 1u);   // RNE
    return (unsigned short)(u >> 16);
}
__device__ __forceinline__ float b2f(unsigned short s){
    unsigned int u = ((unsigned int)s) << 16;
    return __builtin_bit_cast(float, u);
}

__device__ __forceinline__ void gl_lds16(const void* g, void* l){
    __builtin_amdgcn_global_load_lds(
        (const __attribute__((address_space(1))) void*)g,
        (__attribute__((address_space(3))) void*)l, 16, 0, 0);
}

// ---------------- x -> bf16 (padded) + zero cnt, one pass ----------------
__global__ void k_x2b(const float* __restrict__ x, unsigned short* __restrict__ xb,
                      int* __restrict__ cnt){
    int gi = blockIdx.x * 256 + threadIdx.x;
    if (gi < NREP * CSTR) cnt[gi] = 0;
    size_t e0 = (size_t)gi * 8;
    if (e0 >= (size_t)M_PAD * 128) return;
    bf16x8 o;
    if ((e0 >> 7) < N_NODES){
        const float4* xp = (const float4*)(x + e0);
        float4 a = xp[0], b = xp[1];
        o[0] = (short)f2b(a.x); o[1] = (short)f2b(a.y);
        o[2] = (short)f2b(a.z); o[3] = (short)f2b(a.w);
        o[4] = (short)f2b(b.x); o[5] = (short)f2b(b.y);
        o[6] = (short)f2b(b.z); o[7] = (short)f2b(b.w);
    } else {
#pragma unroll
        for (int i = 0; i < 8; ++i) o[i] = 0;
    }
    *(bf16x8*)(xb + e0) = o;
}

// ---------------- replicated bucket-CSR scatter ----------------
__global__ void k_scatter(const int* __restrict__ ei, int* __restrict__ cnt,
                          unsigned short* __restrict__ csr){
    int e = blockIdx.x * 256 + threadIdx.x;
    if (e < N_EDGES){
        unsigned d = (unsigned)ei[N_EDGES + e];
        unsigned s = (unsigned)ei[e];
        if (d < N_NODES && s < N_NODES){
            int r = threadIdx.x & 3;
            int p = atomicAdd(&cnt[r * CSTR + d], 1);
            if (p < RCAP) csr[(((d << 2) + r) << 5) + p] = (unsigned short)s;
        }
    }
}

// ---------------- channel-sliced XCD-resident aggregation ----------------
// out[n] = bf16( in[n] + sum_{j in N(n)} in[j] ), in/out bf16 [M][C].
// Channels split into NG=C/32 groups of 32ch (64B = 1 cache line). Group is
// derived from blockIdx%8 so (assuming round-robin block->XCD) each XCD only
// ever touches ONE 64B column slice: working set 50048*64B = 3.2MB < 4MB L2
// -> gathers become L2 hits; fills drop ~8x. For C=128 (NG=4) the two XCDs
// sharing a group split the destination-node range (SPLIT).
// Thread org: quad (4 lanes x 16B) = one (node, replica-bucket) stream;
// 4 nodes/wave, 16 nodes/block; bucket processed 4-deep (ushort4 broadcast);
// bucket partials combined with shfl_xor(4)+shfl_xor(8); r==0 quad adds the
// self row and stores the 64B output slice.
template<int C, bool SPLIT>
__global__ __launch_bounds__(256) void k_aggx(const unsigned short* __restrict__ in,
        const int* __restrict__ cnt, const unsigned short* __restrict__ csr,
        unsigned short* __restrict__ out){
    constexpr int RS = C / 8;              // row length in bf16x8 chunks
    const int bid = blockIdx.x;
    const int w8 = bid & 7;
    int g, nbase;
    if (SPLIT){                            // C=128: NG=4, XCD pair splits nodes
        g = w8 & 3;
        nbase = ((bid >> 3) + (w8 >> 2) * 1564) * 16;
    } else {                               // C=256: NG=8
        g = w8;
        nbase = (bid >> 3) * 16;
    }
    const int lane = threadIdx.x & 63, wid = threadIdx.x >> 6;
    const int qd = lane >> 2, lq = lane & 3;
    const int nl = qd >> 2, r = qd & 3;
    const int n = nbase + wid * 4 + nl;    // < 50048 by construction
    const int co = g * 4 + lq;             // bf16x8 chunk offset within row

    float a[8];
#pragma unroll
    for (int i = 0; i < 8; ++i) a[i] = 0.f;

    const bf16x8* xr = (const bf16x8*)in;
    if (n < N_NODES){
        int cr = cnt[r * CSTR + n];
        if (cr > RCAP) cr = RCAP;
        const int base = ((n << 2) + r) << 5;
        int k = 0;
        for (; k + 3 < cr; k += 4){
            ushort4 jj = *(const ushort4*)&csr[base + k];   // quad-broadcast
            bf16x8 v0 = xr[(size_t)jj.x * RS + co];
            bf16x8 v1 = xr[(size_t)jj.y * RS + co];
            bf16x8 v2 = xr[(size_t)jj.z * RS + co];
            bf16x8 v3 = xr[(size_t)jj.w * RS + co];
#pragma unroll
            for (int i = 0; i < 8; ++i)
                a[i] += (b2f((unsigned short)v0[i]) + b2f((unsigned short)v1[i]))
                      + (b2f((unsigned short)v2[i]) + b2f((unsigned short)v3[i]));
        }
        for (; k < cr; ++k){
            int j = csr[base + k];
            bf16x8 v = xr[(size_t)j * RS + co];
#pragma unroll
            for (int i = 0; i < 8; ++i) a[i] += b2f((unsigned short)v[i]);
        }
    }
    // combine the 4 bucket streams of this node (lane xor flips r bits only)
#pragma unroll
    for (int i = 0; i < 8; ++i){
        a[i] += __shfl_xor(a[i], 4);
        a[i] += __shfl_xor(a[i], 8);
    }
    if (r == 0){
        bf16x8 o;
        if (n < N_NODES){
            bf16x8 s = xr[(size_t)n * RS + co];
#pragma unroll
            for (int i = 0; i < 8; ++i) o[i] = (short)f2b(a[i] + b2f((unsigned short)s[i]));
        } else {
#pragma unroll
            for (int i = 0; i < 8; ++i) o[i] = 0;   // pad rows -> zeros
        }
        *(bf16x8*)&out[((size_t)n * RS + co) * 8] = o;
    }
}

// ---------------- weight convert+transpose (all 6 in one launch) ----------------
__global__ void k_wt_all(const float* w0, const float* w1, const float* w2,
                         const float* w3, const float* w4, const float* w5,
                         unsigned short* o0, unsigned short* o1, unsigned short* o2,
                         unsigned short* o3, unsigned short* o4, unsigned short* o5){
    const int Ks[6]  = {128, 256, 256, 256, 256, 256};
    const int Ns[6]  = {256, 256, 256, 256, 256,  64};
    const int NPs[6] = {256, 256, 256, 256, 256, 128};
    int s = blockIdx.y;
    const float* w = (s == 0) ? w0 : (s == 1) ? w1 : (s == 2) ? w2
                   : (s == 3) ? w3 : (s == 4) ? w4 : w5;
    unsigned short* o = (s == 0) ? o0 : (s == 1) ? o1 : (s == 2) ? o2
                      : (s == 3) ? o3 : (s == 4) ? o4 : o5;
    int K = Ks[s], N = Ns[s], NP = NPs[s];
    int idx = blockIdx.x * 256 + threadIdx.x;
    if (idx >= NP * K) return;
    int np = idx / K, k = idx - np * K;
    float v = (np < N) ? w[(size_t)k * N + np] : 0.f;
    o[idx] = f2b(v);
}

// ---------------- fused MLP pair (round-8 structure, unchanged) ----------------
template<int K1, int NMID, int NOUT, bool RELU_OUT, bool BF16OUT>
__global__ __launch_bounds__(256) void k_mlp2(const unsigned short* __restrict__ A,
        const unsigned short* __restrict__ WA, const float* __restrict__ bA,
        const unsigned short* __restrict__ WB, const float* __restrict__ bB,
        void* __restrict__ out, int mstore){
    constexpr int NFA = NMID / 32;
    constexpr int NFB = NOUT / 32;
    __shared__ alignas(16) unsigned short As[64 * 32];
    __shared__ alignas(16) unsigned short Bs[NMID * 32];
    __shared__ alignas(16) unsigned short T[64 * TSTR];
    const int tid  = threadIdx.x;
    const int lane = tid & 63;
    const int c = lane & 15, qq = lane >> 4;
    const int kk = qq * 8;
    const int row0 = blockIdx.x * 64;
    const int wm = (tid >> 6) >> 1, wn = (tid >> 6) & 1;

    const f32x4 fzero = {0.f, 0.f, 0.f, 0.f};
    const char* Ab = (const char*)A;

    // ---------- stage A ----------
    {
        f32x4 acc[NFA][2];
#pragma unroll
        for (int nf = 0; nf < NFA; ++nf){ acc[nf][0] = fzero; acc[nf][1] = fzero; }
        const char* Wb = (const char*)WA;
        for (int kt = 0; kt < K1 / 32; ++kt){
            {
                const int o = tid * 16;
                gl_lds16(Ab + ((size_t)(row0 + (o >> 6)) * K1 + kt * 32) * 2 + (o & 63),
                         (char*)As + o);
            }
#pragma unroll
            for (int ch = 0; ch < NMID / 64; ++ch){
                const int o = ch * 4096 + tid * 16;
                gl_lds16(Wb + ((size_t)(o >> 6) * K1 + kt * 32) * 2 + (o & 63),
                         (char*)Bs + o);
            }
            __syncthreads();
            bf16x8 xf[2];
#pragma unroll
            for (int mf = 0; mf < 2; ++mf)
                xf[mf] = *(const bf16x8*)&As[(wm * 32 + mf * 16 + c) * 32 + kk];
#pragma unroll
            for (int nf = 0; nf < NFA; ++nf){
                bf16x8 wf = *(const bf16x8*)&Bs[((wn * NFA + nf) * 16 + c) * 32 + kk];
#pragma unroll
                for (int mf = 0; mf < 2; ++mf)
                    acc[nf][mf] = __builtin_amdgcn_mfma_f32_16x16x32_bf16(wf, xf[mf], acc[nf][mf], 0, 0, 0);
            }
            __syncthreads();
        }
#pragma unroll
        for (int nf = 0; nf < NFA; ++nf){
            const int nb = wn * (NFA * 16) + nf * 16 + qq * 4;
            const float4 bb = *(const float4*)&bA[nb];
#pragma unroll
            for (int mf = 0; mf < 2; ++mf){
                const int ml = wm * 32 + mf * 16 + c;
                float v0 = fmaxf(acc[nf][mf][0] + bb.x, 0.f);
                float v1 = fmaxf(acc[nf][mf][1] + bb.y, 0.f);
                float v2 = fmaxf(acc[nf][mf][2] + bb.z, 0.f);
                float v3 = fmaxf(acc[nf][mf][3] + bb.w, 0.f);
                uint2 p;
                p.x = (unsigned)f2b(v0) | ((unsigned)f2b(v1) << 16);
                p.y = (unsigned)f2b(v2) | ((unsigned)f2b(v3) << 16);
                *(uint2*)&T[ml * TSTR + nb] = p;
            }
        }
    }
    __syncthreads();

    // ---------- stage B ----------
    {
        f32x4 acc[NFB][2];
#pragma unroll
        for (int nf = 0; nf < NFB; ++nf){ acc[nf][0] = fzero; acc[nf][1] = fzero; }
        const char* Wb = (const char*)WB;
        for (int kt = 0; kt < NMID / 32; ++kt){
#pragma unroll
            for (int ch = 0; ch < NOUT / 64; ++ch){
                const int o = ch * 4096 + tid * 16;
                gl_lds16(Wb + ((size_t)(o >> 6) * NMID + kt * 32) * 2 + (o & 63),
                         (char*)Bs + o);
            }
            __syncthreads();
            bf16x8 xf[2];
#pragma unroll
            for (int mf = 0; mf < 2; ++mf)
                xf[mf] = *(const bf16x8*)&T[(wm * 32 + mf * 16 + c) * TSTR + kt * 32 + kk];
#pragma unroll
            for (int nf = 0; nf < NFB; ++nf){
                bf16x8 wf = *(const bf16x8*)&Bs[((wn * NFB + nf) * 16 + c) * 32 + kk];
#pragma unroll
                for (int mf = 0; mf < 2; ++mf)
                    acc[nf][mf] = __builtin_amdgcn_mfma_f32_16x16x32_bf16(wf, xf[mf], acc[nf][mf], 0, 0, 0);
            }
            __syncthreads();
        }
#pragma unroll
        for (int nf = 0; nf < NFB; ++nf){
            const int nb = wn * (NFB * 16) + nf * 16 + qq * 4;
            const float4 bb = *(const float4*)&bB[nb];
#pragma unroll
            for (int mf = 0; mf < 2; ++mf){
                const int m = row0 + wm * 32 + mf * 16 + c;
                if (m < mstore){
                    float v0 = acc[nf][mf][0] + bb.x;
                    float v1 = acc[nf][mf][1] + bb.y;
                    float v2 = acc[nf][mf][2] + bb.z;
                    float v3 = acc[nf][mf][3] + bb.w;
                    if (RELU_OUT){
                        v0 = fmaxf(v0, 0.f); v1 = fmaxf(v1, 0.f);
                        v2 = fmaxf(v2, 0.f); v3 = fmaxf(v3, 0.f);
                    }
                    if (BF16OUT){
                        uint2 p;
                        p.x = (unsigned)f2b(v0) | ((unsigned)f2b(v1) << 16);
                        p.y = (unsigned)f2b(v2) | ((unsigned)f2b(v3) << 16);
                        *(uint2*)&((unsigned short*)out)[(size_t)m * NOUT + nb] = p;
                    } else {
                        float4 p = make_float4(v0, v1, v2, v3);
                        *(float4*)&((float*)out)[(size_t)m * NOUT + nb] = p;
                    }
                }
            }
        }
    }
}

// ---------------- launch ----------------
extern "C" void kernel_launch(void* const* d_in, const int* in_sizes, int n_in,
                              void* d_out, int out_size, void* d_ws, size_t ws_size,
                              hipStream_t stream){
    const float* x   = (const float*)d_in[0];
    const int*   ei  = (const int*)d_in[1];
    const float* w1a = (const float*)d_in[2];
    const float* b1a = (const float*)d_in[3];
    const float* w1b = (const float*)d_in[4];
    const float* b1b = (const float*)d_in[5];
    const float* w2a = (const float*)d_in[6];
    const float* b2a = (const float*)d_in[7];
    const float* w2b = (const float*)d_in[8];
    const float* b2b = (const float*)d_in[9];
    const float* w3a = (const float*)d_in[10];
    const float* b3a = (const float*)d_in[11];
    const float* w3b = (const float*)d_in[12];
    const float* b3b = (const float*)d_in[13];

    char* ws = (char*)d_ws;
    size_t off = 0;
    auto take = [&](size_t bytes) -> char* {
        off = (off + 255) & ~(size_t)255;
        char* p = ws + off;
        off += bytes;
        return p;
    };
    unsigned short* xb   = (unsigned short*)take((size_t)M_PAD * 128 * 2);
    unsigned short* g1   = (unsigned short*)take((size_t)M_PAD * 128 * 2);
    unsigned short* h1   = (unsigned short*)take((size_t)M_PAD * 256 * 2);
    unsigned short* g2   = (unsigned short*)take((size_t)M_PAD * 256 * 2);
    unsigned short* h2   = (unsigned short*)take((size_t)M_PAD * 256 * 2);
    unsigned short* wt1a = (unsigned short*)take(256 * 128 * 2);
    unsigned short* wt1b = (unsigned short*)take(256 * 256 * 2);
    unsigned short* wt2a = (unsigned short*)take(256 * 256 * 2);
    unsigned short* wt2b = (unsigned short*)take(256 * 256 * 2);
    unsigned short* wt3a = (unsigned short*)take(256 * 256 * 2);
    unsigned short* wt3b = (unsigned short*)take(128 * 256 * 2);
    int*            cnt  = (int*)take((size_t)NREP * CSTR * 4);
    unsigned short* csr  = (unsigned short*)take((size_t)N_NODES * NREP * RCAP * 2);

    k_x2b<<<(M_PAD * 128 / 8 + 255) / 256, 256, 0, stream>>>(x, xb, cnt);
    k_scatter<<<(N_EDGES + 255) / 256, 256, 0, stream>>>(ei, cnt, csr);
    k_wt_all<<<dim3(256, 6), 256, 0, stream>>>(w1a, w1b, w2a, w2b, w3a, w3b,
                                               wt1a, wt1b, wt2a, wt2b, wt3a, wt3b);

    // conv1: sliced agg (NG=4, XCD pairs split nodes) -> fused MLP
    k_aggx<128, true ><<<1564 * 8, 256, 0, stream>>>(xb, cnt, csr, g1);
    k_mlp2<128, 256, 256, true, true><<<M_PAD / 64, 256, 0, stream>>>(
        g1, wt1a, b1a, wt1b, b1b, h1, M_PAD);
    // conv2: sliced agg (NG=8) -> fused MLP
    k_aggx<256, false><<<3128 * 8, 256, 0, stream>>>(h1, cnt, csr, g2);
    k_mlp2<256, 256, 256, true, true><<<M_PAD / 64, 256, 0, stream>>>(
        g2, wt2a, b2a, wt2b, b2b, h2, M_PAD);
    // head
    k_mlp2<256, 256, 64, false, false><<<M_PAD / 64, 256, 0, stream>>>(
        h2, wt3a, b3a, wt3b, b3b, d_out, N_NODES);
}

// Round 10
// 235.207 us; speedup vs baseline: 1.2595x; 1.2595x over previous
//
#include <hip/hip_runtime.h>
#include <stdint.h>

#define N_NODES 50000
#define N_EDGES 800000
#define M_PAD   50048   // 391 * 128 (= 3128 * 16)
#define NREP    4       // buckets per node (scatter contention /4)
#define MCAP    8       // main bucket slots (node's 4 buckets = 64B = 1 line)
#define SCAP    24      // spill slots per bucket (P(deg_bucket>32) ~ 1e-9)
#define CSTR    50048   // cnt replica stride
#define TSTR    264     // LDS intermediate-tile row stride (bf16)

typedef __attribute__((ext_vector_type(8))) short bf16x8;
typedef __attribute__((ext_vector_type(4))) float f32x4;

__device__ __forceinline__ unsigned short f2b(float f){
    unsigned int u = __builtin_bit_cast(unsigned int, f);
    u += 0x7fffu + ((u >> 16) & 1u);   // RNE
    return (unsigned short)(u >> 16);
}
__device__ __forceinline__ float b2f(unsigned short s){
    unsigned int u = ((unsigned int)s) << 16;
    return __builtin_bit_cast(float, u);
}

__device__ __forceinline__ void gl_lds16(const void* g, void* l){
    __builtin_amdgcn_global_load_lds(
        (const __attribute__((address_space(1))) void*)g,
        (__attribute__((address_space(3))) void*)l, 16, 0, 0);
}

// ---------------- x -> bf16 SLICED [4][50048][32ch] + zero cnt ----------------
__global__ void k_x2b(const float* __restrict__ x, unsigned short* __restrict__ xs,
                      int* __restrict__ cnt){
    int gi = blockIdx.x * 256 + threadIdx.x;
    if (gi < NREP * CSTR) cnt[gi] = 0;
    size_t e0 = (size_t)gi * 8;
    if (e0 >= (size_t)M_PAD * 128) return;
    int node = (int)(e0 >> 7);
    int ch0  = (int)(e0 & 127);
    int sl = ch0 >> 5, wth = ch0 & 31;
    bf16x8 o;
    if (node < N_NODES){
        const float4* xp = (const float4*)(x + e0);
        float4 a = xp[0], b = xp[1];
        o[0] = (short)f2b(a.x); o[1] = (short)f2b(a.y);
        o[2] = (short)f2b(a.z); o[3] = (short)f2b(a.w);
        o[4] = (short)f2b(b.x); o[5] = (short)f2b(b.y);
        o[6] = (short)f2b(b.z); o[7] = (short)f2b(b.w);
    } else {
#pragma unroll
        for (int i = 0; i < 8; ++i) o[i] = 0;   // pad rows zero in every slice
    }
    *(bf16x8*)&xs[((size_t)(sl * 50048 + node)) * 32 + wth] = o;
}

// ---------------- bucket scatter: main (8 slots) + spill (24 slots) ----------------
__global__ void k_scatter(const int* __restrict__ ei, int* __restrict__ cnt,
                          unsigned short* __restrict__ mn, unsigned short* __restrict__ sp){
    int e = blockIdx.x * 256 + threadIdx.x;
    if (e < N_EDGES){
        unsigned d = (unsigned)ei[N_EDGES + e];
        unsigned s = (unsigned)ei[e];
        if (d < N_NODES && s < N_NODES){
            int r = threadIdx.x & 3;
            int p = atomicAdd(&cnt[r * CSTR + d], 1);
            int b = (d << 2) + r;
            if (p < MCAP) mn[(b << 3) + p] = (unsigned short)s;
            else if (p < MCAP + SCAP) sp[b * SCAP + (p - MCAP)] = (unsigned short)s;
        }
    }
}

// ---------------- channel-sliced XCD-resident aggregation ----------------
// in: SLICED [NG][50048][32ch] (contiguous 3.2MB per slice -> full L2 set use).
// out: ROW-MAJOR [M_PAD][C]. group g from blockIdx%8 (round-robin block->XCD).
// quad (4 lanes x 16B) = one (node, bucket r) stream; invalid slots gather the
// known-zero pad row (jz=50000) -> fixed 4/8 independent gathers, no 0*NaN.
template<int C, bool SPLIT>
__global__ __launch_bounds__(256) void k_aggx(const unsigned short* __restrict__ in,
        const int* __restrict__ cnt, const unsigned short* __restrict__ mn,
        const unsigned short* __restrict__ sp, unsigned short* __restrict__ out){
    constexpr int RS = C / 8;
    const int bid = blockIdx.x, w8 = bid & 7;
    int g, nbase;
    if (SPLIT){ g = w8 & 3; nbase = ((bid >> 3) + (w8 >> 2) * 1564) * 16; }
    else      { g = w8;     nbase = (bid >> 3) * 16; }
    const int lane = threadIdx.x & 63, wid = threadIdx.x >> 6;
    const int qd = lane >> 2, lq = lane & 3;
    const int nl = qd >> 2, r = qd & 3;
    const int n = nbase + wid * 4 + nl;          // < M_PAD by construction
    const bf16x8* xr = (const bf16x8*)in;
    const size_t sb = (size_t)g * 50048;
    const int jz = N_NODES;                      // zeroed pad row

    float a[8];
#pragma unroll
    for (int i = 0; i < 8; ++i) a[i] = 0.f;

    int c = cnt[r * CSTR + n];
    int cr = (c > MCAP + SCAP) ? (MCAP + SCAP) : c;
    int c8 = (cr > MCAP) ? MCAP : cr;
    const unsigned short* mb = &mn[((n << 2) + r) << 3];
    ushort4 u0 = *(const ushort4*)mb;
    ushort4 u1 = *(const ushort4*)(mb + 4);

    {
        int j0 = (c8 > 0) ? (int)u0.x : jz;
        int j1 = (c8 > 1) ? (int)u0.y : jz;
        int j2 = (c8 > 2) ? (int)u0.z : jz;
        int j3 = (c8 > 3) ? (int)u0.w : jz;
        bf16x8 v0 = xr[(sb + j0) * 4 + lq];
        bf16x8 v1 = xr[(sb + j1) * 4 + lq];
        bf16x8 v2 = xr[(sb + j2) * 4 + lq];
        bf16x8 v3 = xr[(sb + j3) * 4 + lq];
#pragma unroll
        for (int i = 0; i < 8; ++i)
            a[i] += (b2f((unsigned short)v0[i]) + b2f((unsigned short)v1[i]))
                  + (b2f((unsigned short)v2[i]) + b2f((unsigned short)v3[i]));
    }
    if (c8 > 4){
        int j4 = (int)u1.x;
        int j5 = (c8 > 5) ? (int)u1.y : jz;
        int j6 = (c8 > 6) ? (int)u1.z : jz;
        int j7 = (c8 > 7) ? (int)u1.w : jz;
        bf16x8 v0 = xr[(sb + j4) * 4 + lq];
        bf16x8 v1 = xr[(sb + j5) * 4 + lq];
        bf16x8 v2 = xr[(sb + j6) * 4 + lq];
        bf16x8 v3 = xr[(sb + j7) * 4 + lq];
#pragma unroll
        for (int i = 0; i < 8; ++i)
            a[i] += (b2f((unsigned short)v0[i]) + b2f((unsigned short)v1[i]))
                  + (b2f((unsigned short)v2[i]) + b2f((unsigned short)v3[i]));
    }
    if (cr > MCAP){                               // rare (~2% of buckets)
        const unsigned short* sb2 = &sp[((n << 2) + r) * SCAP];
        for (int k = MCAP; k < cr; ++k){
            int j = sb2[k - MCAP];
            bf16x8 v = xr[(sb + j) * 4 + lq];
#pragma unroll
            for (int i = 0; i < 8; ++i) a[i] += b2f((unsigned short)v[i]);
        }
    }
    // combine the 4 bucket streams (xor flips r bits only)
#pragma unroll
    for (int i = 0; i < 8; ++i){
        a[i] += __shfl_xor(a[i], 4);
        a[i] += __shfl_xor(a[i], 8);
    }
    if (r == 0){
        bf16x8 o;
        if (n < N_NODES){
            bf16x8 s = xr[(sb + n) * 4 + lq];
#pragma unroll
            for (int i = 0; i < 8; ++i) o[i] = (short)f2b(a[i] + b2f((unsigned short)s[i]));
        } else {
#pragma unroll
            for (int i = 0; i < 8; ++i) o[i] = 0;
        }
        *(bf16x8*)&out[((size_t)n * RS + g * 4 + lq) * 8] = o;
    }
}

// ---------------- weight convert+transpose (all 6 in one launch) ----------------
__global__ void k_wt_all(const float* w0, const float* w1, const float* w2,
                         const float* w3, const float* w4, const float* w5,
                         unsigned short* o0, unsigned short* o1, unsigned short* o2,
                         unsigned short* o3, unsigned short* o4, unsigned short* o5){
    const int Ks[6]  = {128, 256, 256, 256, 256, 256};
    const int Ns[6]  = {256, 256, 256, 256, 256,  64};
    const int NPs[6] = {256, 256, 256, 256, 256, 128};
    int s = blockIdx.y;
    const float* w = (s == 0) ? w0 : (s == 1) ? w1 : (s == 2) ? w2
                   : (s == 3) ? w3 : (s == 4) ? w4 : w5;
    unsigned short* o = (s == 0) ? o0 : (s == 1) ? o1 : (s == 2) ? o2
                      : (s == 3) ? o3 : (s == 4) ? o4 : o5;
    int K = Ks[s], N = Ns[s], NP = NPs[s];
    int idx = blockIdx.x * 256 + threadIdx.x;
    if (idx >= NP * K) return;
    int np = idx / K, k = idx - np * K;
    float v = (np < N) ? w[(size_t)k * N + np] : 0.f;
    o[idx] = f2b(v);
}

// ---------------- fused MLP pair ----------------
// SLICED: write bf16 output in [8][50048][32ch] layout, rows >= N_NODES zeroed.
template<int K1, int NMID, int NOUT, bool RELU_OUT, bool BF16OUT, bool SLICED>
__global__ __launch_bounds__(256) void k_mlp2(const unsigned short* __restrict__ A,
        const unsigned short* __restrict__ WA, const float* __restrict__ bA,
        const unsigned short* __restrict__ WB, const float* __restrict__ bB,
        void* __restrict__ out, int mstore){
    constexpr int NFA = NMID / 32;
    constexpr int NFB = NOUT / 32;
    __shared__ alignas(16) unsigned short As[64 * 32];
    __shared__ alignas(16) unsigned short Bs[NMID * 32];
    __shared__ alignas(16) unsigned short T[64 * TSTR];
    const int tid  = threadIdx.x;
    const int lane = tid & 63;
    const int c = lane & 15, qq = lane >> 4;
    const int kk = qq * 8;
    const int row0 = blockIdx.x * 64;
    const int wm = (tid >> 6) >> 1, wn = (tid >> 6) & 1;

    const f32x4 fzero = {0.f, 0.f, 0.f, 0.f};
    const char* Ab = (const char*)A;

    // ---------- stage A ----------
    {
        f32x4 acc[NFA][2];
#pragma unroll
        for (int nf = 0; nf < NFA; ++nf){ acc[nf][0] = fzero; acc[nf][1] = fzero; }
        const char* Wb = (const char*)WA;
        for (int kt = 0; kt < K1 / 32; ++kt){
            {
                const int o = tid * 16;
                gl_lds16(Ab + ((size_t)(row0 + (o >> 6)) * K1 + kt * 32) * 2 + (o & 63),
                         (char*)As + o);
            }
#pragma unroll
            for (int ch = 0; ch < NMID / 64; ++ch){
                const int o = ch * 4096 + tid * 16;
                gl_lds16(Wb + ((size_t)(o >> 6) * K1 + kt * 32) * 2 + (o & 63),
                         (char*)Bs + o);
            }
            __syncthreads();
            bf16x8 xf[2];
#pragma unroll
            for (int mf = 0; mf < 2; ++mf)
                xf[mf] = *(const bf16x8*)&As[(wm * 32 + mf * 16 + c) * 32 + kk];
#pragma unroll
            for (int nf = 0; nf < NFA; ++nf){
                bf16x8 wf = *(const bf16x8*)&Bs[((wn * NFA + nf) * 16 + c) * 32 + kk];
#pragma unroll
                for (int mf = 0; mf < 2; ++mf)
                    acc[nf][mf] = __builtin_amdgcn_mfma_f32_16x16x32_bf16(wf, xf[mf], acc[nf][mf], 0, 0, 0);
            }
            __syncthreads();
        }
#pragma unroll
        for (int nf = 0; nf < NFA; ++nf){
            const int nb = wn * (NFA * 16) + nf * 16 + qq * 4;
            const float4 bb = *(const float4*)&bA[nb];
#pragma unroll
            for (int mf = 0; mf < 2; ++mf){
                const int ml = wm * 32 + mf * 16 + c;
                float v0 = fmaxf(acc[nf][mf][0] + bb.x, 0.f);
                float v1 = fmaxf(acc[nf][mf][1] + bb.y, 0.f);
                float v2 = fmaxf(acc[nf][mf][2] + bb.z, 0.f);
                float v3 = fmaxf(acc[nf][mf][3] + bb.w, 0.f);
                uint2 p;
                p.x = (unsigned)f2b(v0) | ((unsigned)f2b(v1) << 16);
                p.y = (unsigned)f2b(v2) | ((unsigned)f2b(v3) << 16);
                *(uint2*)&T[ml * TSTR + nb] = p;
            }
        }
    }
    __syncthreads();

    // ---------- stage B ----------
    {
        f32x4 acc[NFB][2];
#pragma unroll
        for (int nf = 0; nf < NFB; ++nf){ acc[nf][0] = fzero; acc[nf][1] = fzero; }
        const char* Wb = (const char*)WB;
        for (int kt = 0; kt < NMID / 32; ++kt){
#pragma unroll
            for (int ch = 0; ch < NOUT / 64; ++ch){
                const int o = ch * 4096 + tid * 16;
                gl_lds16(Wb + ((size_t)(o >> 6) * NMID + kt * 32) * 2 + (o & 63),
                         (char*)Bs + o);
            }
            __syncthreads();
            bf16x8 xf[2];
#pragma unroll
            for (int mf = 0; mf < 2; ++mf)
                xf[mf] = *(const bf16x8*)&T[(wm * 32 + mf * 16 + c) * TSTR + kt * 32 + kk];
#pragma unroll
            for (int nf = 0; nf < NFB; ++nf){
                bf16x8 wf = *(const bf16x8*)&Bs[((wn * NFB + nf) * 16 + c) * 32 + kk];
#pragma unroll
                for (int mf = 0; mf < 2; ++mf)
                    acc[nf][mf] = __builtin_amdgcn_mfma_f32_16x16x32_bf16(wf, xf[mf], acc[nf][mf], 0, 0, 0);
            }
            __syncthreads();
        }
#pragma unroll
        for (int nf = 0; nf < NFB; ++nf){
            const int nb = wn * (NFB * 16) + nf * 16 + qq * 4;
            const float4 bb = *(const float4*)&bB[nb];
#pragma unroll
            for (int mf = 0; mf < 2; ++mf){
                const int m = row0 + wm * 32 + mf * 16 + c;
                if (m < mstore){
                    float v0 = acc[nf][mf][0] + bb.x;
                    float v1 = acc[nf][mf][1] + bb.y;
                    float v2 = acc[nf][mf][2] + bb.z;
                    float v3 = acc[nf][mf][3] + bb.w;
                    if (RELU_OUT){
                        v0 = fmaxf(v0, 0.f); v1 = fmaxf(v1, 0.f);
                        v2 = fmaxf(v2, 0.f); v3 = fmaxf(v3, 0.f);
                    }
                    if (SLICED){
                        uint2 p;
                        p.x = (unsigned)f2b(v0) | ((unsigned)f2b(v1) << 16);
                        p.y = (unsigned)f2b(v2) | ((unsigned)f2b(v3) << 16);
                        if (m >= N_NODES){ p.x = 0; p.y = 0; }   // zero pad rows
                        *(uint2*)&((unsigned short*)out)[
                            ((size_t)((nb >> 5) * 50048 + m)) * 32 + (nb & 31)] = p;
                    } else if (BF16OUT){
                        uint2 p;
                        p.x = (unsigned)f2b(v0) | ((unsigned)f2b(v1) << 16);
                        p.y = (unsigned)f2b(v2) | ((unsigned)f2b(v3) << 16);
                        *(uint2*)&((unsigned short*)out)[(size_t)m * NOUT + nb] = p;
                    } else {
                        float4 p = make_float4(v0, v1, v2, v3);
                        *(float4*)&((float*)out)[(size_t)m * NOUT + nb] = p;
                    }
                }
            }
        }
    }
}

// ---------------- launch ----------------
extern "C" void kernel_launch(void* const* d_in, const int* in_sizes, int n_in,
                              void* d_out, int out_size, void* d_ws, size_t ws_size,
                              hipStream_t stream){
    const float* x   = (const float*)d_in[0];
    const int*   ei  = (const int*)d_in[1];
    const float* w1a = (const float*)d_in[2];
    const float* b1a = (const float*)d_in[3];
    const float* w1b = (const float*)d_in[4];
    const float* b1b = (const float*)d_in[5];
    const float* w2a = (const float*)d_in[6];
    const float* b2a = (const float*)d_in[7];
    const float* w2b = (const float*)d_in[8];
    const float* b2b = (const float*)d_in[9];
    const float* w3a = (const float*)d_in[10];
    const float* b3a = (const float*)d_in[11];
    const float* w3b = (const float*)d_in[12];
    const float* b3b = (const float*)d_in[13];

    char* ws = (char*)d_ws;
    size_t off = 0;
    auto take = [&](size_t bytes) -> char* {
        off = (off + 255) & ~(size_t)255;
        char* p = ws + off;
        off += bytes;
        return p;
    };
    unsigned short* xs1  = (unsigned short*)take((size_t)4 * 50048 * 32 * 2);  // x sliced
    unsigned short* g1   = (unsigned short*)take((size_t)M_PAD * 128 * 2);     // agg1 out (row-major)
    unsigned short* h1s  = (unsigned short*)take((size_t)8 * 50048 * 32 * 2);  // h1 sliced
    unsigned short* g2   = (unsigned short*)take((size_t)M_PAD * 256 * 2);     // agg2 out (row-major)
    unsigned short* h2   = (unsigned short*)take((size_t)M_PAD * 256 * 2);
    unsigned short* wt1a = (unsigned short*)take(256 * 128 * 2);
    unsigned short* wt1b = (unsigned short*)take(256 * 256 * 2);
    unsigned short* wt2a = (unsigned short*)take(256 * 256 * 2);
    unsigned short* wt2b = (unsigned short*)take(256 * 256 * 2);
    unsigned short* wt3a = (unsigned short*)take(256 * 256 * 2);
    unsigned short* wt3b = (unsigned short*)take(128 * 256 * 2);
    int*            cnt  = (int*)take((size_t)NREP * CSTR * 4);
    unsigned short* mn   = (unsigned short*)take((size_t)M_PAD * 4 * MCAP * 2);
    unsigned short* sp   = (unsigned short*)take((size_t)M_PAD * 4 * SCAP * 2);

    k_x2b<<<(M_PAD * 128 / 8 + 255) / 256, 256, 0, stream>>>(x, xs1, cnt);
    k_scatter<<<(N_EDGES + 255) / 256, 256, 0, stream>>>(ei, cnt, mn, sp);
    k_wt_all<<<dim3(256, 6), 256, 0, stream>>>(w1a, w1b, w2a, w2b, w3a, w3b,
                                               wt1a, wt1b, wt2a, wt2b, wt3a, wt3b);

    // conv1: sliced agg (NG=4, XCD pairs split node range) -> fused MLP -> h1 sliced
    k_aggx<128, true ><<<1564 * 8, 256, 0, stream>>>(xs1, cnt, mn, sp, g1);
    k_mlp2<128, 256, 256, true, true, true><<<M_PAD / 64, 256, 0, stream>>>(
        g1, wt1a, b1a, wt1b, b1b, h1s, M_PAD);
    // conv2: sliced agg (NG=8) -> fused MLP
    k_aggx<256, false><<<3128 * 8, 256, 0, stream>>>(h1s, cnt, mn, sp, g2);
    k_mlp2<256, 256, 256, true, true, false><<<M_PAD / 64, 256, 0, stream>>>(
        g2, wt2a, b2a, wt2b, b2b, h2, M_PAD);
    // head
    k_mlp2<256, 256, 64, false, false, false><<<M_PAD / 64, 256, 0, stream>>>(
        h2, wt3a, b3a, wt3b, b3b, d_out, N_NODES);
}